// Round 6
// baseline (381.618 us; speedup 1.0000x reference)
//
#include <hip/hip_runtime.h>
#include <hip/hip_fp16.h>
#include <math.h>

#define NN 100000
#define NE 1600000
#define D  64
#define NBLK 391  // ceil(NN/256)

typedef _Float16 half2v __attribute__((ext_vector_type(2)));

// ---------------- K_prep: zn = z/||z|| and x, both fp16, interleaved [n][128]; cnt=0 ----------------
__global__ __launch_bounds__(256) void k_prep(const float* __restrict__ z,
                                              const float* __restrict__ x,
                                              __half* __restrict__ zxh,
                                              int* __restrict__ cnt) {
    int wave = (blockIdx.x * blockDim.x + threadIdx.x) >> 6;
    int lane = threadIdx.x & 63;
    if (wave >= NN) return;
    float v = z[wave * D + lane];
    float s = v * v;
#pragma unroll
    for (int off = 32; off; off >>= 1) s += __shfl_xor(s, off);
    float inv = 1.0f / sqrtf(fmaxf(s, 1e-18f));
    zxh[wave * 128 + lane] = __float2half(v * inv);
    zxh[wave * 128 + 64 + lane] = __float2half(x[wave * D + lane]);
    if (lane == 0) cnt[wave] = 0;
}

// ---------------- K_count: edges per destination row ----------------
__global__ __launch_bounds__(256) void k_count(const int* __restrict__ ei,
                                               int* __restrict__ cnt) {
    int i = blockIdx.x * blockDim.x + threadIdx.x;
    int stride = gridDim.x * blockDim.x;
    for (int e = i; e < NE; e += stride) atomicAdd(&cnt[ei[e]], 1);
}

// ---------------- scan: exclusive prefix sum of cnt -> row_start, cursor ----------------
__global__ __launch_bounds__(256) void k_scan1(const int* __restrict__ cnt,
                                               int* __restrict__ inc,
                                               int* __restrict__ bsum) {
    __shared__ int sh[256];
    int gid = blockIdx.x * 256 + threadIdx.x;
    int v = (gid < NN) ? cnt[gid] : 0;
    sh[threadIdx.x] = v;
    __syncthreads();
    for (int off = 1; off < 256; off <<= 1) {
        int t = (threadIdx.x >= off) ? sh[threadIdx.x - off] : 0;
        __syncthreads();
        sh[threadIdx.x] += t;
        __syncthreads();
    }
    if (gid < NN) inc[gid] = sh[threadIdx.x];
    if (threadIdx.x == 255) bsum[blockIdx.x] = sh[255];
}

__global__ __launch_bounds__(512) void k_scan2(int* __restrict__ bsum) {
    __shared__ int sh[512];
    int v = (threadIdx.x < NBLK) ? bsum[threadIdx.x] : 0;
    sh[threadIdx.x] = v;
    __syncthreads();
    for (int off = 1; off < 512; off <<= 1) {
        int t = (threadIdx.x >= off) ? sh[threadIdx.x - off] : 0;
        __syncthreads();
        sh[threadIdx.x] += t;
        __syncthreads();
    }
    if (threadIdx.x < NBLK) bsum[threadIdx.x] = sh[threadIdx.x] - v;  // exclusive
}

__global__ __launch_bounds__(256) void k_scan3(const int* __restrict__ cnt,
                                               const int* __restrict__ inc,
                                               const int* __restrict__ bsum,
                                               int* __restrict__ row_start,
                                               int* __restrict__ cursor) {
    int gid = blockIdx.x * 256 + threadIdx.x;
    if (gid < NN) {
        int ex = inc[gid] - cnt[gid] + bsum[blockIdx.x];
        row_start[gid] = ex;
        cursor[gid] = ex;
    }
}

// ---------------- K_edge_place: in-lane dot + exp + CSR placement of {col, ex} ----------------
__global__ __launch_bounds__(256) void k_edge_place(const __half* __restrict__ zxh,
                                                    const int* __restrict__ ei,
                                                    const float* __restrict__ alpha_p,
                                                    const float* __restrict__ bias_p,
                                                    int* __restrict__ cursor,
                                                    int2* __restrict__ packed) {
    int e = blockIdx.x * 256 + threadIdx.x;
    if (e >= NE) return;
    const float alpha = *alpha_p;
    const float bias = *bias_p;
    const float Mest = fabsf(alpha) + bias;  // >= max logit since |corr| <= 1 (fp16 slack ~1e-3, harmless)
    int r = ei[e];
    int c = ei[NE + e];
    const float4* zi4 = (const float4*)(zxh + (size_t)r * 128);
    const float4* zj4 = (const float4*)(zxh + (size_t)c * 128);
    float4 a[8], bb[8];
#pragma unroll
    for (int k = 0; k < 8; ++k) { a[k] = zi4[k]; bb[k] = zj4[k]; }
    float dot = 0.0f;
#pragma unroll
    for (int k = 0; k < 8; ++k) {
        const half2v* ha = (const half2v*)&a[k];
        const half2v* hb = (const half2v*)&bb[k];
#pragma unroll
        for (int q = 0; q < 4; ++q) {
#if defined(__has_builtin) && __has_builtin(__builtin_amdgcn_fdot2)
            dot = __builtin_amdgcn_fdot2(ha[q], hb[q], dot, false);
#else
            float2 fa = __half22float2(*(const __half2*)&ha[q]);
            float2 fb = __half22float2(*(const __half2*)&hb[q]);
            dot = fmaf(fa.x, fb.x, dot);
            dot = fmaf(fa.y, fb.y, dot);
#endif
        }
    }
    float ex = __expf(alpha * dot + bias - Mest);
    int pos = atomicAdd(&cursor[r], 1);
    packed[pos] = make_int2(c, __float_as_int(ex));
}

// ---------------- K_gather: grid-stride wave per node, broadcast+fma, fused linear ----------------
__global__ __launch_bounds__(256) void k_gather(const __half* __restrict__ zxh,
                                                const int2* __restrict__ packed,
                                                const int* __restrict__ row_start,
                                                const int* __restrict__ cnt,
                                                const float* __restrict__ W,
                                                const float* __restrict__ b,
                                                float* __restrict__ out) {
    __shared__ float Wt[64 * 65];  // Wt[d*65 + j] = W[j*64 + d]
    __shared__ float bs[64];
    for (int i = threadIdx.x; i < 4096; i += blockDim.x) {
        Wt[(i & 63) * 65 + (i >> 6)] = W[i];
    }
    if (threadIdx.x < 64) bs[threadIdx.x] = b[threadIdx.x];
    __syncthreads();
    const int lane = threadIdx.x & 63;
    const int wpb = blockDim.x >> 6;
    int wave = blockIdx.x * wpb + (threadIdx.x >> 6);
    int nWaves = gridDim.x * wpb;
    for (int n = wave; n < NN; n += nWaves) {
        int rs = row_start[n];
        int c = cnt[n];
        float acc = 0.0f;
        float dsum = 0.0f;
        for (int base = 0; base < c; base += 64) {
            int m = min(64, c - base);
            int idx = base + lane;
            int2 p = (idx < c) ? packed[rs + idx] : make_int2(0, 0);
            float ev = __int_as_float(p.y);
            // chunk-wide denom sum (one butterfly per 64 edges)
            float t = ev;
#pragma unroll
            for (int off = 32; off; off >>= 1) t += __shfl_xor(t, off);
            dsum += t;
            int j = 0;
            for (; j + 8 <= m; j += 8) {
                int c0 = __builtin_amdgcn_readlane(p.x, j);
                int c1 = __builtin_amdgcn_readlane(p.x, j + 1);
                int c2 = __builtin_amdgcn_readlane(p.x, j + 2);
                int c3 = __builtin_amdgcn_readlane(p.x, j + 3);
                int c4 = __builtin_amdgcn_readlane(p.x, j + 4);
                int c5 = __builtin_amdgcn_readlane(p.x, j + 5);
                int c6 = __builtin_amdgcn_readlane(p.x, j + 6);
                int c7 = __builtin_amdgcn_readlane(p.x, j + 7);
                float e0 = __int_as_float(__builtin_amdgcn_readlane(p.y, j));
                float e1 = __int_as_float(__builtin_amdgcn_readlane(p.y, j + 1));
                float e2 = __int_as_float(__builtin_amdgcn_readlane(p.y, j + 2));
                float e3 = __int_as_float(__builtin_amdgcn_readlane(p.y, j + 3));
                float e4 = __int_as_float(__builtin_amdgcn_readlane(p.y, j + 4));
                float e5 = __int_as_float(__builtin_amdgcn_readlane(p.y, j + 5));
                float e6 = __int_as_float(__builtin_amdgcn_readlane(p.y, j + 6));
                float e7 = __int_as_float(__builtin_amdgcn_readlane(p.y, j + 7));
                float x0 = __half2float(zxh[(size_t)c0 * 128 + 64 + lane]);
                float x1 = __half2float(zxh[(size_t)c1 * 128 + 64 + lane]);
                float x2 = __half2float(zxh[(size_t)c2 * 128 + 64 + lane]);
                float x3 = __half2float(zxh[(size_t)c3 * 128 + 64 + lane]);
                float x4 = __half2float(zxh[(size_t)c4 * 128 + 64 + lane]);
                float x5 = __half2float(zxh[(size_t)c5 * 128 + 64 + lane]);
                float x6 = __half2float(zxh[(size_t)c6 * 128 + 64 + lane]);
                float x7 = __half2float(zxh[(size_t)c7 * 128 + 64 + lane]);
                acc = fmaf(e0, x0, acc);
                acc = fmaf(e1, x1, acc);
                acc = fmaf(e2, x2, acc);
                acc = fmaf(e3, x3, acc);
                acc = fmaf(e4, x4, acc);
                acc = fmaf(e5, x5, acc);
                acc = fmaf(e6, x6, acc);
                acc = fmaf(e7, x7, acc);
            }
            for (; j < m; ++j) {
                int c0 = __builtin_amdgcn_readlane(p.x, j);
                float e0 = __int_as_float(__builtin_amdgcn_readlane(p.y, j));
                float x0 = __half2float(zxh[(size_t)c0 * 128 + 64 + lane]);
                acc = fmaf(e0, x0, acc);
            }
        }
        float a = acc / (dsum + 1e-9f);
        // epilogue: out = a @ Wt + b, 4 independent fma chains
        float w0 = bs[lane], w1 = 0.0f, w2 = 0.0f, w3 = 0.0f;
#pragma unroll
        for (int d = 0; d < 64; d += 4) {
            w0 = fmaf(__shfl(a, d), Wt[d * 65 + lane], w0);
            w1 = fmaf(__shfl(a, d + 1), Wt[(d + 1) * 65 + lane], w1);
            w2 = fmaf(__shfl(a, d + 2), Wt[(d + 2) * 65 + lane], w2);
            w3 = fmaf(__shfl(a, d + 3), Wt[(d + 3) * 65 + lane], w3);
        }
        out[n * D + lane] = (w0 + w1) + (w2 + w3);
    }
}

extern "C" void kernel_launch(void* const* d_in, const int* in_sizes, int n_in,
                              void* d_out, int out_size, void* d_ws, size_t ws_size,
                              hipStream_t stream) {
    const float* x = (const float*)d_in[0];
    const int* ei = (const int*)d_in[1];  // [2, NE] int32
    const float* z = (const float*)d_in[2];
    const float* W = (const float*)d_in[3];
    const float* b = (const float*)d_in[4];
    const float* alpha = (const float*)d_in[5];
    const float* bias_edge = (const float*)d_in[6];
    float* out = (float*)d_out;  // [NN, D]

    // workspace layout
    char* ws = (char*)d_ws;
    size_t off = 0;
    __half* zxh = (__half*)(ws + off); off += (size_t)NN * 128 * 2;   // 25.6 MB
    int2* packed = (int2*)(ws + off); off += (size_t)NE * 8;          // 12.8 MB
    int* cnt = (int*)(ws + off); off += (size_t)NN * 4;
    int* inc = (int*)(ws + off); off += (size_t)NN * 4;
    int* row_start = (int*)(ws + off); off += (size_t)NN * 4;
    int* cursor = (int*)(ws + off); off += (size_t)NN * 4;
    int* bsum = (int*)(ws + off); off += 512 * 4;

    k_prep<<<(NN * 64 + 255) / 256, 256, 0, stream>>>(z, x, zxh, cnt);
    k_count<<<2048, 256, 0, stream>>>(ei, cnt);
    k_scan1<<<NBLK, 256, 0, stream>>>(cnt, inc, bsum);
    k_scan2<<<1, 512, 0, stream>>>(bsum);
    k_scan3<<<NBLK, 256, 0, stream>>>(cnt, inc, bsum, row_start, cursor);
    k_edge_place<<<(NE + 255) / 256, 256, 0, stream>>>(zxh, ei, alpha, bias_edge, cursor, packed);
    k_gather<<<2048, 256, 0, stream>>>(zxh, packed, row_start, cnt, W, b, out);
}

// Round 7
// 314.019 us; speedup vs baseline: 1.2153x; 1.2153x over previous
//
#include <hip/hip_runtime.h>
#include <hip/hip_fp16.h>
#include <math.h>

#define NN 100000
#define NE 1600000
#define D  64
#define NBLK 391  // ceil(NN/256)

typedef _Float16 half2v __attribute__((ext_vector_type(2)));

// ---------------- K_prep: znh = z/||z|| (fp16), xwh = x @ W^T (fp16); cnt=0 ----------------
__global__ __launch_bounds__(256) void k_prep(const float* __restrict__ z,
                                              const float* __restrict__ x,
                                              const float* __restrict__ W,
                                              __half* __restrict__ znh,
                                              __half* __restrict__ xwh,
                                              int* __restrict__ cnt) {
    __shared__ float Wt[64 * 65];  // Wt[d*65 + j] = W[j*64 + d]
    for (int i = threadIdx.x; i < 4096; i += 256) {
        Wt[(i & 63) * 65 + (i >> 6)] = W[i];
    }
    __syncthreads();
    const int lane = threadIdx.x & 63;
    int wave = blockIdx.x * 4 + (threadIdx.x >> 6);
    int nWaves = gridDim.x * 4;
    for (int n = wave; n < NN; n += nWaves) {
        float zv = z[n * D + lane];
        float s = zv * zv;
#pragma unroll
        for (int off = 32; off; off >>= 1) s += __shfl_xor(s, off);
        float inv = 1.0f / sqrtf(fmaxf(s, 1e-18f));
        znh[n * D + lane] = __float2half(zv * inv);
        float xv = x[n * D + lane];
        float y0 = 0.0f, y1 = 0.0f, y2 = 0.0f, y3 = 0.0f;
#pragma unroll
        for (int d = 0; d < 64; d += 4) {
            y0 = fmaf(__shfl(xv, d), Wt[d * 65 + lane], y0);
            y1 = fmaf(__shfl(xv, d + 1), Wt[(d + 1) * 65 + lane], y1);
            y2 = fmaf(__shfl(xv, d + 2), Wt[(d + 2) * 65 + lane], y2);
            y3 = fmaf(__shfl(xv, d + 3), Wt[(d + 3) * 65 + lane], y3);
        }
        xwh[n * D + lane] = __float2half((y0 + y1) + (y2 + y3));
        if (lane == 0) cnt[n] = 0;
    }
}

// ---------------- K_count: edges per destination row ----------------
__global__ __launch_bounds__(256) void k_count(const int* __restrict__ ei,
                                               int* __restrict__ cnt) {
    int i = blockIdx.x * blockDim.x + threadIdx.x;
    int stride = gridDim.x * blockDim.x;
    for (int e = i; e < NE; e += stride) atomicAdd(&cnt[ei[e]], 1);
}

// ---------------- scan: exclusive prefix sum of cnt -> row_start, cursor ----------------
__global__ __launch_bounds__(256) void k_scan1(const int* __restrict__ cnt,
                                               int* __restrict__ inc,
                                               int* __restrict__ bsum) {
    __shared__ int sh[256];
    int gid = blockIdx.x * 256 + threadIdx.x;
    int v = (gid < NN) ? cnt[gid] : 0;
    sh[threadIdx.x] = v;
    __syncthreads();
    for (int off = 1; off < 256; off <<= 1) {
        int t = (threadIdx.x >= off) ? sh[threadIdx.x - off] : 0;
        __syncthreads();
        sh[threadIdx.x] += t;
        __syncthreads();
    }
    if (gid < NN) inc[gid] = sh[threadIdx.x];
    if (threadIdx.x == 255) bsum[blockIdx.x] = sh[255];
}

__global__ __launch_bounds__(512) void k_scan2(int* __restrict__ bsum) {
    __shared__ int sh[512];
    int v = (threadIdx.x < NBLK) ? bsum[threadIdx.x] : 0;
    sh[threadIdx.x] = v;
    __syncthreads();
    for (int off = 1; off < 512; off <<= 1) {
        int t = (threadIdx.x >= off) ? sh[threadIdx.x - off] : 0;
        __syncthreads();
        sh[threadIdx.x] += t;
        __syncthreads();
    }
    if (threadIdx.x < NBLK) bsum[threadIdx.x] = sh[threadIdx.x] - v;  // exclusive
}

__global__ __launch_bounds__(256) void k_scan3(const int* __restrict__ cnt,
                                               const int* __restrict__ inc,
                                               const int* __restrict__ bsum,
                                               int* __restrict__ row_start,
                                               int* __restrict__ cursor) {
    int gid = blockIdx.x * 256 + threadIdx.x;
    if (gid < NN) {
        int ex = inc[gid] - cnt[gid] + bsum[blockIdx.x];
        row_start[gid] = ex;
        cursor[gid] = ex;
    }
}

// ---------------- K_edge_place: in-lane dot + exp + CSR placement of {col, ex} ----------------
__global__ __launch_bounds__(256) void k_edge_place(const __half* __restrict__ znh,
                                                    const int* __restrict__ ei,
                                                    const float* __restrict__ alpha_p,
                                                    const float* __restrict__ bias_p,
                                                    int* __restrict__ cursor,
                                                    int2* __restrict__ packed) {
    int e = blockIdx.x * 256 + threadIdx.x;
    if (e >= NE) return;
    const float alpha = *alpha_p;
    const float bias = *bias_p;
    const float Mest = fabsf(alpha) + bias;  // >= max logit since |corr| <= 1
    int r = ei[e];
    int c = ei[NE + e];
    const float4* zi4 = (const float4*)(znh + (size_t)r * D);
    const float4* zj4 = (const float4*)(znh + (size_t)c * D);
    float4 a[8], bb[8];
#pragma unroll
    for (int k = 0; k < 8; ++k) { a[k] = zi4[k]; bb[k] = zj4[k]; }
    float dot = 0.0f;
#pragma unroll
    for (int k = 0; k < 8; ++k) {
        const half2v* ha = (const half2v*)&a[k];
        const half2v* hb = (const half2v*)&bb[k];
#pragma unroll
        for (int q = 0; q < 4; ++q) {
#if defined(__has_builtin) && __has_builtin(__builtin_amdgcn_fdot2)
            dot = __builtin_amdgcn_fdot2(ha[q], hb[q], dot, false);
#else
            float2 fa = __half22float2(*(const __half2*)&ha[q]);
            float2 fb = __half22float2(*(const __half2*)&hb[q]);
            dot = fmaf(fa.x, fb.x, dot);
            dot = fmaf(fa.y, fb.y, dot);
#endif
        }
    }
    float ex = __expf(alpha * dot + bias - Mest);
    int pos = atomicAdd(&cursor[r], 1);
    packed[pos] = make_int2(c, __float_as_int(ex));
}

// ---------------- K_gather: one wave per node, scalar-addressed y-row gather, no LDS ----------------
__global__ __launch_bounds__(256) void k_gather(const __half* __restrict__ xwh,
                                                const int2* __restrict__ packed,
                                                const int* __restrict__ row_start,
                                                const int* __restrict__ cnt,
                                                const float* __restrict__ b,
                                                float* __restrict__ out) {
    const int lane = threadIdx.x & 63;
    int n = (blockIdx.x * blockDim.x + threadIdx.x) >> 6;  // one wave per node
    if (n >= NN) return;
    int rs = row_start[n];
    int c = cnt[n];
    float bv = b[lane];
    float acc = 0.0f;
    float dsum = 0.0f;
    for (int base = 0; base < c; base += 64) {
        int m = min(64, c - base);
        int idx = base + lane;
        int2 p = (idx < c) ? packed[rs + idx] : make_int2(0, 0);
        // chunk-wide denom sum (one butterfly per 64 edges)
        float t = __int_as_float(p.y);
#pragma unroll
        for (int off = 32; off; off >>= 1) t += __shfl_xor(t, off);
        dsum += t;
        int j = 0;
        for (; j + 8 <= m; j += 8) {
            // cols/exps become wave-uniform (SGPR) -> scalar row bases, invariant lane offset
            int c0 = __builtin_amdgcn_readlane(p.x, j);
            int c1 = __builtin_amdgcn_readlane(p.x, j + 1);
            int c2 = __builtin_amdgcn_readlane(p.x, j + 2);
            int c3 = __builtin_amdgcn_readlane(p.x, j + 3);
            int c4 = __builtin_amdgcn_readlane(p.x, j + 4);
            int c5 = __builtin_amdgcn_readlane(p.x, j + 5);
            int c6 = __builtin_amdgcn_readlane(p.x, j + 6);
            int c7 = __builtin_amdgcn_readlane(p.x, j + 7);
            float e0 = __int_as_float(__builtin_amdgcn_readlane(p.y, j));
            float e1 = __int_as_float(__builtin_amdgcn_readlane(p.y, j + 1));
            float e2 = __int_as_float(__builtin_amdgcn_readlane(p.y, j + 2));
            float e3 = __int_as_float(__builtin_amdgcn_readlane(p.y, j + 3));
            float e4 = __int_as_float(__builtin_amdgcn_readlane(p.y, j + 4));
            float e5 = __int_as_float(__builtin_amdgcn_readlane(p.y, j + 5));
            float e6 = __int_as_float(__builtin_amdgcn_readlane(p.y, j + 6));
            float e7 = __int_as_float(__builtin_amdgcn_readlane(p.y, j + 7));
            float x0 = __half2float(xwh[(size_t)c0 * D + lane]);
            float x1 = __half2float(xwh[(size_t)c1 * D + lane]);
            float x2 = __half2float(xwh[(size_t)c2 * D + lane]);
            float x3 = __half2float(xwh[(size_t)c3 * D + lane]);
            float x4 = __half2float(xwh[(size_t)c4 * D + lane]);
            float x5 = __half2float(xwh[(size_t)c5 * D + lane]);
            float x6 = __half2float(xwh[(size_t)c6 * D + lane]);
            float x7 = __half2float(xwh[(size_t)c7 * D + lane]);
            acc = fmaf(e0, x0, acc);
            acc = fmaf(e1, x1, acc);
            acc = fmaf(e2, x2, acc);
            acc = fmaf(e3, x3, acc);
            acc = fmaf(e4, x4, acc);
            acc = fmaf(e5, x5, acc);
            acc = fmaf(e6, x6, acc);
            acc = fmaf(e7, x7, acc);
        }
        for (; j < m; ++j) {
            int c0 = __builtin_amdgcn_readlane(p.x, j);
            float e0 = __int_as_float(__builtin_amdgcn_readlane(p.y, j));
            float x0 = __half2float(xwh[(size_t)c0 * D + lane]);
            acc = fmaf(e0, x0, acc);
        }
    }
    out[n * D + lane] = acc / (dsum + 1e-9f) + bv;
}

extern "C" void kernel_launch(void* const* d_in, const int* in_sizes, int n_in,
                              void* d_out, int out_size, void* d_ws, size_t ws_size,
                              hipStream_t stream) {
    const float* x = (const float*)d_in[0];
    const int* ei = (const int*)d_in[1];  // [2, NE] int32
    const float* z = (const float*)d_in[2];
    const float* W = (const float*)d_in[3];
    const float* b = (const float*)d_in[4];
    const float* alpha = (const float*)d_in[5];
    const float* bias_edge = (const float*)d_in[6];
    float* out = (float*)d_out;  // [NN, D]

    // workspace layout
    char* ws = (char*)d_ws;
    size_t off = 0;
    __half* znh = (__half*)(ws + off); off += (size_t)NN * D * 2;     // 12.8 MB
    __half* xwh = (__half*)(ws + off); off += (size_t)NN * D * 2;     // 12.8 MB
    int2* packed = (int2*)(ws + off); off += (size_t)NE * 8;          // 12.8 MB
    int* cnt = (int*)(ws + off); off += (size_t)NN * 4;
    int* inc = (int*)(ws + off); off += (size_t)NN * 4;
    int* row_start = (int*)(ws + off); off += (size_t)NN * 4;
    int* cursor = (int*)(ws + off); off += (size_t)NN * 4;
    int* bsum = (int*)(ws + off); off += 512 * 4;

    k_prep<<<2048, 256, 0, stream>>>(z, x, W, znh, xwh, cnt);
    k_count<<<2048, 256, 0, stream>>>(ei, cnt);
    k_scan1<<<NBLK, 256, 0, stream>>>(cnt, inc, bsum);
    k_scan2<<<1, 512, 0, stream>>>(bsum);
    k_scan3<<<NBLK, 256, 0, stream>>>(cnt, inc, bsum, row_start, cursor);
    k_edge_place<<<(NE + 255) / 256, 256, 0, stream>>>(znh, ei, alpha, bias_edge, cursor, packed);
    k_gather<<<(NN * 64 + 255) / 256, 256, 0, stream>>>(xwh, packed, row_start, cnt, b, out);
}

// Round 8
// 312.544 us; speedup vs baseline: 1.2210x; 1.0047x over previous
//
#include <hip/hip_runtime.h>
#include <hip/hip_fp16.h>
#include <math.h>

#define NN 100000
#define NE 1600000
#define D  64
#define NBLK 391  // ceil(NN/256)

typedef _Float16 half2v __attribute__((ext_vector_type(2)));

// packed CSR entry: [col:17][ex_fp16_no_sign:15]  (col < 2^17, ex > 0)
__device__ __forceinline__ unsigned int pack_entry(int col, float ex) {
    unsigned short hb = __half_as_ushort(__float2half(ex));
    return ((unsigned int)col << 15) | (unsigned int)(hb & 0x7FFFu);
}
__device__ __forceinline__ float unpack_ex(unsigned int pk) {
    return __half2float(__ushort_as_half((unsigned short)(pk & 0x7FFFu)));
}

// ---------------- K_prep: znh = z/||z|| (fp16), xwh = x @ W^T (fp16); cnt=0 ----------------
__global__ __launch_bounds__(256) void k_prep(const float* __restrict__ z,
                                              const float* __restrict__ x,
                                              const float* __restrict__ W,
                                              __half* __restrict__ znh,
                                              __half* __restrict__ xwh,
                                              int* __restrict__ cnt) {
    __shared__ float Wt[64 * 65];  // Wt[d*65 + j] = W[j*64 + d]
    for (int i = threadIdx.x; i < 4096; i += 256) {
        Wt[(i & 63) * 65 + (i >> 6)] = W[i];
    }
    __syncthreads();
    const int lane = threadIdx.x & 63;
    int wave = blockIdx.x * 4 + (threadIdx.x >> 6);
    int nWaves = gridDim.x * 4;
    for (int n = wave; n < NN; n += nWaves) {
        float zv = z[n * D + lane];
        float s = zv * zv;
#pragma unroll
        for (int off = 32; off; off >>= 1) s += __shfl_xor(s, off);
        float inv = 1.0f / sqrtf(fmaxf(s, 1e-18f));
        znh[n * D + lane] = __float2half(zv * inv);
        float xv = x[n * D + lane];
        float y0 = 0.0f, y1 = 0.0f, y2 = 0.0f, y3 = 0.0f;
#pragma unroll
        for (int d = 0; d < 64; d += 4) {
            y0 = fmaf(__shfl(xv, d), Wt[d * 65 + lane], y0);
            y1 = fmaf(__shfl(xv, d + 1), Wt[(d + 1) * 65 + lane], y1);
            y2 = fmaf(__shfl(xv, d + 2), Wt[(d + 2) * 65 + lane], y2);
            y3 = fmaf(__shfl(xv, d + 3), Wt[(d + 3) * 65 + lane], y3);
        }
        xwh[n * D + lane] = __float2half((y0 + y1) + (y2 + y3));
        if (lane == 0) cnt[n] = 0;
    }
}

// ---------------- K_count: edges per destination row ----------------
__global__ __launch_bounds__(256) void k_count(const int* __restrict__ ei,
                                               int* __restrict__ cnt) {
    int i = blockIdx.x * blockDim.x + threadIdx.x;
    int stride = gridDim.x * blockDim.x;
    for (int e = i; e < NE; e += stride) atomicAdd(&cnt[ei[e]], 1);
}

// ---------------- scan: exclusive prefix sum of cnt -> row_start, cursor ----------------
__global__ __launch_bounds__(256) void k_scan1(const int* __restrict__ cnt,
                                               int* __restrict__ inc,
                                               int* __restrict__ bsum) {
    __shared__ int sh[256];
    int gid = blockIdx.x * 256 + threadIdx.x;
    int v = (gid < NN) ? cnt[gid] : 0;
    sh[threadIdx.x] = v;
    __syncthreads();
    for (int off = 1; off < 256; off <<= 1) {
        int t = (threadIdx.x >= off) ? sh[threadIdx.x - off] : 0;
        __syncthreads();
        sh[threadIdx.x] += t;
        __syncthreads();
    }
    if (gid < NN) inc[gid] = sh[threadIdx.x];
    if (threadIdx.x == 255) bsum[blockIdx.x] = sh[255];
}

__global__ __launch_bounds__(512) void k_scan2(int* __restrict__ bsum) {
    __shared__ int sh[512];
    int v = (threadIdx.x < NBLK) ? bsum[threadIdx.x] : 0;
    sh[threadIdx.x] = v;
    __syncthreads();
    for (int off = 1; off < 512; off <<= 1) {
        int t = (threadIdx.x >= off) ? sh[threadIdx.x - off] : 0;
        __syncthreads();
        sh[threadIdx.x] += t;
        __syncthreads();
    }
    if (threadIdx.x < NBLK) bsum[threadIdx.x] = sh[threadIdx.x] - v;  // exclusive
}

__global__ __launch_bounds__(256) void k_scan3(const int* __restrict__ cnt,
                                               const int* __restrict__ inc,
                                               const int* __restrict__ bsum,
                                               int* __restrict__ row_start,
                                               int* __restrict__ cursor) {
    int gid = blockIdx.x * 256 + threadIdx.x;
    if (gid < NN) {
        int ex = inc[gid] - cnt[gid] + bsum[blockIdx.x];
        row_start[gid] = ex;
        cursor[gid] = ex;
    }
}

// ---------------- K_edge_place: in-lane dot + exp + 4B CSR placement ----------------
__global__ __launch_bounds__(256) void k_edge_place(const __half* __restrict__ znh,
                                                    const int* __restrict__ ei,
                                                    const float* __restrict__ alpha_p,
                                                    const float* __restrict__ bias_p,
                                                    int* __restrict__ cursor,
                                                    unsigned int* __restrict__ packed) {
    int e = blockIdx.x * 256 + threadIdx.x;
    if (e >= NE) return;
    const float alpha = *alpha_p;
    const float bias = *bias_p;
    const float Mest = fabsf(alpha) + bias;  // >= max logit since |corr| <= 1
    int r = ei[e];
    int c = ei[NE + e];
    const float4* zi4 = (const float4*)(znh + (size_t)r * D);
    const float4* zj4 = (const float4*)(znh + (size_t)c * D);
    float4 a[8], bb[8];
#pragma unroll
    for (int k = 0; k < 8; ++k) { a[k] = zi4[k]; bb[k] = zj4[k]; }
    float dot = 0.0f;
#pragma unroll
    for (int k = 0; k < 8; ++k) {
        const half2v* ha = (const half2v*)&a[k];
        const half2v* hb = (const half2v*)&bb[k];
#pragma unroll
        for (int q = 0; q < 4; ++q) {
#if defined(__has_builtin) && __has_builtin(__builtin_amdgcn_fdot2)
            dot = __builtin_amdgcn_fdot2(ha[q], hb[q], dot, false);
#else
            float2 fa = __half22float2(*(const __half2*)&ha[q]);
            float2 fb = __half22float2(*(const __half2*)&hb[q]);
            dot = fmaf(fa.x, fb.x, dot);
            dot = fmaf(fa.y, fb.y, dot);
#endif
        }
    }
    float ex = __expf(alpha * dot + bias - Mest);
    int pos = atomicAdd(&cursor[r], 1);
    packed[pos] = pack_entry(c, ex);
}

// ---------------- K_gather: one wave per node, scalar-addressed y-row gather, no LDS ----------------
__global__ __launch_bounds__(256) void k_gather(const __half* __restrict__ xwh,
                                                const unsigned int* __restrict__ packed,
                                                const int* __restrict__ row_start,
                                                const int* __restrict__ cnt,
                                                const float* __restrict__ b,
                                                float* __restrict__ out) {
    const int lane = threadIdx.x & 63;
    int n = (blockIdx.x * blockDim.x + threadIdx.x) >> 6;  // one wave per node
    if (n >= NN) return;
    int rs = row_start[n];
    int c = cnt[n];
    float bv = b[lane];
    float acc = 0.0f;
    float dsum = 0.0f;
    for (int base = 0; base < c; base += 64) {
        int m = min(64, c - base);
        int idx = base + lane;
        unsigned int pk = (idx < c) ? packed[rs + idx] : 0u;
        // chunk-wide denom sum (one butterfly per 64 edges); pk==0 -> ev=0
        float t = (idx < c) ? unpack_ex(pk) : 0.0f;
#pragma unroll
        for (int off = 32; off; off >>= 1) t += __shfl_xor(t, off);
        dsum += t;
        int j = 0;
        for (; j + 8 <= m; j += 8) {
            unsigned int p0 = (unsigned int)__builtin_amdgcn_readlane((int)pk, j);
            unsigned int p1 = (unsigned int)__builtin_amdgcn_readlane((int)pk, j + 1);
            unsigned int p2 = (unsigned int)__builtin_amdgcn_readlane((int)pk, j + 2);
            unsigned int p3 = (unsigned int)__builtin_amdgcn_readlane((int)pk, j + 3);
            unsigned int p4 = (unsigned int)__builtin_amdgcn_readlane((int)pk, j + 4);
            unsigned int p5 = (unsigned int)__builtin_amdgcn_readlane((int)pk, j + 5);
            unsigned int p6 = (unsigned int)__builtin_amdgcn_readlane((int)pk, j + 6);
            unsigned int p7 = (unsigned int)__builtin_amdgcn_readlane((int)pk, j + 7);
            float x0 = __half2float(xwh[(size_t)(p0 >> 15) * D + lane]);
            float x1 = __half2float(xwh[(size_t)(p1 >> 15) * D + lane]);
            float x2 = __half2float(xwh[(size_t)(p2 >> 15) * D + lane]);
            float x3 = __half2float(xwh[(size_t)(p3 >> 15) * D + lane]);
            float x4 = __half2float(xwh[(size_t)(p4 >> 15) * D + lane]);
            float x5 = __half2float(xwh[(size_t)(p5 >> 15) * D + lane]);
            float x6 = __half2float(xwh[(size_t)(p6 >> 15) * D + lane]);
            float x7 = __half2float(xwh[(size_t)(p7 >> 15) * D + lane]);
            acc = fmaf(unpack_ex(p0), x0, acc);
            acc = fmaf(unpack_ex(p1), x1, acc);
            acc = fmaf(unpack_ex(p2), x2, acc);
            acc = fmaf(unpack_ex(p3), x3, acc);
            acc = fmaf(unpack_ex(p4), x4, acc);
            acc = fmaf(unpack_ex(p5), x5, acc);
            acc = fmaf(unpack_ex(p6), x6, acc);
            acc = fmaf(unpack_ex(p7), x7, acc);
        }
        for (; j < m; ++j) {
            unsigned int p0 = (unsigned int)__builtin_amdgcn_readlane((int)pk, j);
            float x0 = __half2float(xwh[(size_t)(p0 >> 15) * D + lane]);
            acc = fmaf(unpack_ex(p0), x0, acc);
        }
    }
    out[n * D + lane] = acc / (dsum + 1e-9f) + bv;
}

extern "C" void kernel_launch(void* const* d_in, const int* in_sizes, int n_in,
                              void* d_out, int out_size, void* d_ws, size_t ws_size,
                              hipStream_t stream) {
    const float* x = (const float*)d_in[0];
    const int* ei = (const int*)d_in[1];  // [2, NE] int32
    const float* z = (const float*)d_in[2];
    const float* W = (const float*)d_in[3];
    const float* b = (const float*)d_in[4];
    const float* alpha = (const float*)d_in[5];
    const float* bias_edge = (const float*)d_in[6];
    float* out = (float*)d_out;  // [NN, D]

    // workspace layout
    char* ws = (char*)d_ws;
    size_t off = 0;
    __half* znh = (__half*)(ws + off); off += (size_t)NN * D * 2;       // 12.8 MB
    __half* xwh = (__half*)(ws + off); off += (size_t)NN * D * 2;       // 12.8 MB
    unsigned int* packed = (unsigned int*)(ws + off); off += (size_t)NE * 4;  // 6.4 MB
    int* cnt = (int*)(ws + off); off += (size_t)NN * 4;
    int* inc = (int*)(ws + off); off += (size_t)NN * 4;
    int* row_start = (int*)(ws + off); off += (size_t)NN * 4;
    int* cursor = (int*)(ws + off); off += (size_t)NN * 4;
    int* bsum = (int*)(ws + off); off += 512 * 4;

    k_prep<<<2048, 256, 0, stream>>>(z, x, W, znh, xwh, cnt);
    k_count<<<2048, 256, 0, stream>>>(ei, cnt);
    k_scan1<<<NBLK, 256, 0, stream>>>(cnt, inc, bsum);
    k_scan2<<<1, 512, 0, stream>>>(bsum);
    k_scan3<<<NBLK, 256, 0, stream>>>(cnt, inc, bsum, row_start, cursor);
    k_edge_place<<<(NE + 255) / 256, 256, 0, stream>>>(znh, ei, alpha, bias_edge, cursor, packed);
    k_gather<<<(NN * 64 + 255) / 256, 256, 0, stream>>>(xwh, packed, row_start, cnt, b, out);
}